// Round 1
// 1643.548 us; speedup vs baseline: 1.0468x; 1.0468x over previous
//
#include <hip/hip_runtime.h>
#include <stdint.h>
#include <stddef.h>

#define NE 8
#define HIDDEN 2048
#define INTER 2816
#define NT 8192
#define NROWS (NT * 2)

typedef __bf16 bf16x8 __attribute__((ext_vector_type(8)));
typedef float f32x4 __attribute__((ext_vector_type(4)));

__device__ __forceinline__ unsigned short f2bf(float f) {
  union { float f; uint32_t u; } v; v.f = f;
  uint32_t r = v.u + 0x7FFFu + ((v.u >> 16) & 1u);
  return (unsigned short)(r >> 16);
}

// async global->LDS, 16B per lane. LDS dest must be wave-uniform base + lane*16.
__device__ __forceinline__ void async16(const void* g, const unsigned short* lds_ptr) {
  __builtin_amdgcn_global_load_lds(
      (const __attribute__((address_space(1))) uint32_t*)g,
      (__attribute__((address_space(3))) uint32_t*)lds_ptr,
      16, 0, 0);
}

// ---------------- fp32 -> bf16 conversion (4 elems/thread) ----------------
__global__ void cvt_kernel(const float4* __restrict__ src, ushort4* __restrict__ dst) {
  size_t i = (size_t)blockIdx.x * blockDim.x + threadIdx.x;
  float4 v = src[i];
  ushort4 o;
  o.x = f2bf(v.x); o.y = f2bf(v.y); o.z = f2bf(v.z); o.w = f2bf(v.w);
  dst[i] = o;
}

// ---------------- router: fp32 exact, wave per token ----------------
__global__ __launch_bounds__(256) void router_kernel(
    const float* __restrict__ x, const float* __restrict__ gw,
    int* __restrict__ top_e, float* __restrict__ top_w, int* __restrict__ counts) {
  int t = blockIdx.x * 4 + (threadIdx.x >> 6);
  int lane = threadIdx.x & 63;
  const float* xr = x + (size_t)t * HIDDEN;
  float acc[NE];
#pragma unroll
  for (int e = 0; e < NE; ++e) acc[e] = 0.f;
  for (int kb = 0; kb < HIDDEN; kb += 64) {
    float xv = xr[kb + lane];
#pragma unroll
    for (int e = 0; e < NE; ++e) acc[e] += xv * gw[e * HIDDEN + kb + lane];
  }
#pragma unroll
  for (int e = 0; e < NE; ++e) {
#pragma unroll
    for (int off = 32; off > 0; off >>= 1) acc[e] += __shfl_xor(acc[e], off, 64);
  }
  if (lane == 0) {
    float mx = acc[0];
#pragma unroll
    for (int e = 1; e < NE; ++e) mx = fmaxf(mx, acc[e]);
    float p[NE];
    float s = 0.f;
#pragma unroll
    for (int e = 0; e < NE; ++e) { p[e] = expf(acc[e] - mx); s += p[e]; }
    int e1 = 0;
#pragma unroll
    for (int e = 1; e < NE; ++e) if (p[e] > p[e1]) e1 = e;
    int e2 = (e1 == 0) ? 1 : 0;
#pragma unroll
    for (int e = 0; e < NE; ++e) if (e != e1 && p[e] > p[e2]) e2 = e;
    float inv = 1.f / s;
    top_e[2 * t] = e1; top_e[2 * t + 1] = e2;
    top_w[2 * t] = p[e1] * inv; top_w[2 * t + 1] = p[e2] * inv;
    atomicAdd(&counts[e1], 1);
    atomicAdd(&counts[e2], 1);
  }
}

// ---------------- exclusive scan of 8 counts ----------------
__global__ void scan_kernel(const int* __restrict__ counts, int* __restrict__ offs) {
  if (threadIdx.x == 0) {
    int s = 0;
    for (int e = 0; e < NE; ++e) { offs[e] = s; s += counts[e]; }
    offs[NE] = s;
  }
}

// ---------------- compact row lists + inverse map ----------------
__global__ void fill_kernel(const int* __restrict__ top_e, const float* __restrict__ top_w,
                            const int* __restrict__ offs, int* __restrict__ fillc,
                            int* __restrict__ row_tok, float* __restrict__ row_w,
                            int* __restrict__ row_of) {
  int t = blockIdx.x * 256 + threadIdx.x;
#pragma unroll
  for (int j = 0; j < 2; ++j) {
    int e = top_e[2 * t + j];
    int slot = atomicAdd(&fillc[e], 1);
    int row = offs[e] + slot;
    row_tok[row] = t;
    row_w[row] = top_w[2 * t + j];
    row_of[2 * t + j] = row;
  }
}

// ================= GEMM1: 256x(128 gate||128 up) tile, BK=64, 8-phase =================
// 512 threads, 8 waves (4M x 2N). LDS 128 KiB: [2 buf][2 khalf][A 256 rows | B 256 rows][32 bf16].
// Rows are 32 bf16 (64B); 16B chunks XOR-swizzled by ((row>>1)&3) (proven conflict-free).
// Counted vmcnt(4) twice per K-tile (never 0 in main loop); raw s_barrier only.
__global__ __launch_bounds__(512, 2) void gemm1_kernel(
    const unsigned short* __restrict__ xb, const unsigned short* __restrict__ w13b,
    const int* __restrict__ row_tok, const int* __restrict__ offs,
    unsigned short* __restrict__ hbuf) {
  __shared__ __align__(16) unsigned short smem[2][2][16384];  // 128 KiB
  const int e = blockIdx.z, mt = blockIdx.y, nt = blockIdx.x;
  const int row0 = offs[e];
  const int cnt = offs[e + 1] - row0;
  if (mt * 256 >= cnt) return;
  const int tid = threadIdx.x;

  // staging coords: one issue = 512 lanes x 16B = 128 rows x 64B
  const int lrow = tid >> 2;
  const int gch = ((tid & 3) ^ ((lrow >> 1) & 3)) * 8;  // pre-swizzled source chunk (elems)
  size_t aA[2];
#pragma unroll
  for (int i = 0; i < 2; ++i) {
    int grow = mt * 256 + i * 128 + lrow;
    int rr = row0 + (grow < cnt ? grow : cnt - 1);
    aA[i] = (size_t)row_tok[rr] * HIDDEN + gch;
  }
  const size_t aBg = ((size_t)e * 2 * INTER + nt * 128 + lrow) * (size_t)HIDDEN + gch;
  const size_t aBu = ((size_t)e * 2 * INTER + INTER + nt * 128 + lrow) * (size_t)HIDDEN + gch;

  // fragment coords
  const int wv = tid >> 6, wm = wv >> 1, wn = wv & 1;
  const int l = tid & 63, lm = l & 15, lq = l >> 4;
  const int loff = lm * 32 + ((lq ^ ((lm >> 1) & 3)) * 8);

  f32x4 accg[4][4], accu[4][4];
#pragma unroll
  for (int i = 0; i < 4; ++i)
#pragma unroll
    for (int j = 0; j < 4; ++j) {
      accg[i][j] = (f32x4){0.f, 0.f, 0.f, 0.f};
      accu[i][j] = (f32x4){0.f, 0.f, 0.f, 0.f};
    }

#define ST_A1(NB, KH, KT) do { \
    size_t ko = (size_t)(KT) * 64 + (KH) * 32; \
    async16(xb + aA[0] + ko, &smem[NB][KH][tid * 8]); \
    async16(xb + aA[1] + ko, &smem[NB][KH][4096 + tid * 8]); } while (0)
#define ST_B1(NB, KH, KT) do { \
    size_t ko = (size_t)(KT) * 64 + (KH) * 32; \
    async16(w13b + aBg + ko, &smem[NB][KH][8192 + tid * 8]); \
    async16(w13b + aBu + ko, &smem[NB][KH][12288 + tid * 8]); } while (0)

  // prologue: stage K-tile 0 into buf 0; publish its k0 halves (oldest 4 loads)
  ST_A1(0, 0, 0); ST_B1(0, 0, 0); ST_A1(0, 1, 0); ST_B1(0, 1, 0);
  asm volatile("s_waitcnt vmcnt(4)" ::: "memory");
  __builtin_amdgcn_s_barrier();

  const int NTK = HIDDEN / 64;  // 32
  for (int t = 0; t < NTK; ++t) {
    const int b = t & 1, nb = b ^ 1;
    const bool pf = (t + 1 < NTK);
#pragma unroll
    for (int kk = 0; kk < 2; ++kk) {
      const unsigned short* sK = &smem[b][kk][0];
      bf16x8 af[4], bfr[4];
      // ---- phase (kk, gate): ds-reads || stage A khalf of next tile ----
#pragma unroll
      for (int i = 0; i < 4; ++i)
        af[i] = *(const bf16x8*)(sK + (wm * 64 + i * 16) * 32 + loff);
#pragma unroll
      for (int j = 0; j < 4; ++j)
        bfr[j] = *(const bf16x8*)(sK + (256 + wn * 64 + j * 16) * 32 + loff);
      if (pf) ST_A1(nb, kk, t + 1);
      __builtin_amdgcn_s_barrier();
      asm volatile("s_waitcnt lgkmcnt(0)" ::: "memory");
      __builtin_amdgcn_sched_barrier(0);
      __builtin_amdgcn_s_setprio(1);
#pragma unroll
      for (int i = 0; i < 4; ++i)
#pragma unroll
        for (int j = 0; j < 4; ++j)
          accg[i][j] = __builtin_amdgcn_mfma_f32_16x16x32_bf16(af[i], bfr[j], accg[i][j], 0, 0, 0);
      __builtin_amdgcn_s_setprio(0);
      __builtin_amdgcn_s_barrier();
      // ---- phase (kk, up): ds-reads (A reused) || stage B khalf of next tile ----
#pragma unroll
      for (int j = 0; j < 4; ++j)
        bfr[j] = *(const bf16x8*)(sK + (384 + wn * 64 + j * 16) * 32 + loff);
      if (pf) ST_B1(nb, kk, t + 1);
      if (kk == 0) {
        // publish current tile's k1 halves (oldest 4 of <=8 outstanding)
        if (pf) { asm volatile("s_waitcnt vmcnt(4)" ::: "memory"); }
        else    { asm volatile("s_waitcnt vmcnt(0)" ::: "memory"); }
      } else if (pf) {
        // publish next tile's k0 halves (oldest 4 of 8 outstanding)
        asm volatile("s_waitcnt vmcnt(4)" ::: "memory");
      }
      __builtin_amdgcn_s_barrier();
      asm volatile("s_waitcnt lgkmcnt(0)" ::: "memory");
      __builtin_amdgcn_sched_barrier(0);
      __builtin_amdgcn_s_setprio(1);
#pragma unroll
      for (int i = 0; i < 4; ++i)
#pragma unroll
        for (int j = 0; j < 4; ++j)
          accu[i][j] = __builtin_amdgcn_mfma_f32_16x16x32_bf16(af[i], bfr[j], accu[i][j], 0, 0, 0);
      __builtin_amdgcn_s_setprio(0);
      __builtin_amdgcn_s_barrier();
    }
  }
#undef ST_A1
#undef ST_B1

  // epilogue: h = silu(g) * u
#pragma unroll
  for (int i = 0; i < 4; ++i) {
#pragma unroll
    for (int r = 0; r < 4; ++r) {
      int grow = mt * 256 + wm * 64 + i * 16 + lq * 4 + r;
      if (grow < cnt) {
        size_t hrow = (size_t)(row0 + grow) * INTER + nt * 128 + wn * 64 + lm;
#pragma unroll
        for (int j = 0; j < 4; ++j) {
          float g = accg[i][j][r], u = accu[i][j][r];
          float sg = g / (1.f + expf(-g));
          hbuf[hrow + j * 16] = f2bf(sg * u);
        }
      }
    }
  }
}

// ================= GEMM2: 256x256 tile, BK=64, 8-phase =================
// Same schedule as gemm1; N-frags split 0..3 / 4..7 across the phase pair.
__global__ __launch_bounds__(512, 2) void gemm2_kernel(
    const unsigned short* __restrict__ hbuf, const unsigned short* __restrict__ w2b,
    const float* __restrict__ row_w, const int* __restrict__ offs,
    float* __restrict__ ybuf) {
  __shared__ __align__(16) unsigned short smem[2][2][16384];  // 128 KiB
  const int e = blockIdx.z, mt = blockIdx.y, nt = blockIdx.x;
  const int row0 = offs[e];
  const int cnt = offs[e + 1] - row0;
  if (mt * 256 >= cnt) return;
  const int tid = threadIdx.x;

  const int lrow = tid >> 2;
  const int gch = ((tid & 3) ^ ((lrow >> 1) & 3)) * 8;
  size_t aA[2], aB[2];
#pragma unroll
  for (int i = 0; i < 2; ++i) {
    int grow = mt * 256 + i * 128 + lrow;
    int rr = row0 + (grow < cnt ? grow : cnt - 1);
    aA[i] = (size_t)rr * INTER + gch;
    aB[i] = ((size_t)e * HIDDEN + nt * 256 + i * 128 + lrow) * (size_t)INTER + gch;
  }

  const int wv = tid >> 6, wm = wv >> 1, wn = wv & 1;
  const int l = tid & 63, lm = l & 15, lq = l >> 4;
  const int loff = lm * 32 + ((lq ^ ((lm >> 1) & 3)) * 8);

  f32x4 acc[4][8];
#pragma unroll
  for (int i = 0; i < 4; ++i)
#pragma unroll
    for (int j = 0; j < 8; ++j) acc[i][j] = (f32x4){0.f, 0.f, 0.f, 0.f};

#define ST_A2(NB, KH, KT) do { \
    size_t ko = (size_t)(KT) * 64 + (KH) * 32; \
    async16(hbuf + aA[0] + ko, &smem[NB][KH][tid * 8]); \
    async16(hbuf + aA[1] + ko, &smem[NB][KH][4096 + tid * 8]); } while (0)
#define ST_B2(NB, KH, KT) do { \
    size_t ko = (size_t)(KT) * 64 + (KH) * 32; \
    async16(w2b + aB[0] + ko, &smem[NB][KH][8192 + tid * 8]); \
    async16(w2b + aB[1] + ko, &smem[NB][KH][12288 + tid * 8]); } while (0)

  ST_A2(0, 0, 0); ST_B2(0, 0, 0); ST_A2(0, 1, 0); ST_B2(0, 1, 0);
  asm volatile("s_waitcnt vmcnt(4)" ::: "memory");
  __builtin_amdgcn_s_barrier();

  const int NTK = INTER / 64;  // 44
  for (int t = 0; t < NTK; ++t) {
    const int b = t & 1, nb = b ^ 1;
    const bool pf = (t + 1 < NTK);
#pragma unroll
    for (int kk = 0; kk < 2; ++kk) {
      const unsigned short* sK = &smem[b][kk][0];
      bf16x8 af[4], bfr[4];
#pragma unroll
      for (int i = 0; i < 4; ++i)
        af[i] = *(const bf16x8*)(sK + (wm * 64 + i * 16) * 32 + loff);
#pragma unroll
      for (int j = 0; j < 4; ++j)
        bfr[j] = *(const bf16x8*)(sK + (256 + wn * 128 + j * 16) * 32 + loff);
      if (pf) ST_A2(nb, kk, t + 1);
      __builtin_amdgcn_s_barrier();
      asm volatile("s_waitcnt lgkmcnt(0)" ::: "memory");
      __builtin_amdgcn_sched_barrier(0);
      __builtin_amdgcn_s_setprio(1);
#pragma unroll
      for (int i = 0; i < 4; ++i)
#pragma unroll
        for (int j = 0; j < 4; ++j)
          acc[i][j] = __builtin_amdgcn_mfma_f32_16x16x32_bf16(af[i], bfr[j], acc[i][j], 0, 0, 0);
      __builtin_amdgcn_s_setprio(0);
      __builtin_amdgcn_s_barrier();
#pragma unroll
      for (int j = 0; j < 4; ++j)
        bfr[j] = *(const bf16x8*)(sK + (256 + wn * 128 + (j + 4) * 16) * 32 + loff);
      if (pf) ST_B2(nb, kk, t + 1);
      if (kk == 0) {
        if (pf) { asm volatile("s_waitcnt vmcnt(4)" ::: "memory"); }
        else    { asm volatile("s_waitcnt vmcnt(0)" ::: "memory"); }
      } else if (pf) {
        asm volatile("s_waitcnt vmcnt(4)" ::: "memory");
      }
      __builtin_amdgcn_s_barrier();
      asm volatile("s_waitcnt lgkmcnt(0)" ::: "memory");
      __builtin_amdgcn_sched_barrier(0);
      __builtin_amdgcn_s_setprio(1);
#pragma unroll
      for (int i = 0; i < 4; ++i)
#pragma unroll
        for (int j = 0; j < 4; ++j)
          acc[i][j + 4] = __builtin_amdgcn_mfma_f32_16x16x32_bf16(af[i], bfr[j], acc[i][j + 4], 0, 0, 0);
      __builtin_amdgcn_s_setprio(0);
      __builtin_amdgcn_s_barrier();
    }
  }
#undef ST_A2
#undef ST_B2

#pragma unroll
  for (int i = 0; i < 4; ++i) {
#pragma unroll
    for (int r = 0; r < 4; ++r) {
      int grow = mt * 256 + wm * 64 + i * 16 + lq * 4 + r;
      if (grow < cnt) {
        int rr = row0 + grow;
        float w = row_w[rr];
        float* yrow = ybuf + (size_t)rr * HIDDEN + nt * 256 + wn * 128 + lm;
#pragma unroll
        for (int j = 0; j < 8; ++j) yrow[j * 16] = w * acc[i][j][r];
      }
    }
  }
}

// ---------------- combine: out[t] = ybuf[r0(t)] + ybuf[r1(t)] ----------------
__global__ __launch_bounds__(256) void combine_kernel(
    const float* __restrict__ ybuf, const int* __restrict__ row_of,
    float* __restrict__ out) {
  int t = blockIdx.x;
  int r0 = row_of[2 * t], r1 = row_of[2 * t + 1];
  const float4* y0 = (const float4*)(ybuf + (size_t)r0 * HIDDEN);
  const float4* y1 = (const float4*)(ybuf + (size_t)r1 * HIDDEN);
  float4* o = (float4*)(out + (size_t)t * HIDDEN);
#pragma unroll
  for (int it = 0; it < 2; ++it) {
    int c = it * 256 + threadIdx.x;
    float4 a = y0[c], b = y1[c];
    o[c] = make_float4(a.x + b.x, a.y + b.y, a.z + b.z, a.w + b.w);
  }
}

extern "C" void kernel_launch(void* const* d_in, const int* in_sizes, int n_in,
                              void* d_out, int out_size, void* d_ws, size_t ws_size,
                              hipStream_t stream) {
  const float* x = (const float*)d_in[0];
  const float* gw = (const float*)d_in[1];
  const float* w13 = (const float*)d_in[2];
  const float* w2 = (const float*)d_in[3];
  float* out = (float*)d_out;
  char* ws = (char*)d_ws;

  // workspace layout (bytes)
  int* counts = (int*)(ws + 0);          // 32 B
  int* fillc = (int*)(ws + 32);          // 32 B
  int* offs = (int*)(ws + 64);           // 36 B
  int* top_e = (int*)(ws + 1024);        // 64 KB
  float* top_w = (float*)(ws + 66560);   // 64 KB
  int* row_tok = (int*)(ws + 132096);    // 64 KB
  float* row_w = (float*)(ws + 197632);  // 64 KB
  int* row_of = (int*)(ws + 263168);     // 64 KB -> 328704
  unsigned short* xb = (unsigned short*)(ws + 328704);       // 32 MB -> 33883136
  unsigned short* w13b = (unsigned short*)(ws + 33883136);   // 176 MB -> 218432512
  float* ybuf = (float*)(ws + 33883136);                     // aliases w13b (stream-ordered: gemm1 done before gemm2)
  unsigned short* w2b = (unsigned short*)(ws + 218432512);   // 88 MB -> 310707200
  unsigned short* hb = (unsigned short*)(ws + 310707200);    // 88 MB -> 402981888

  hipMemsetAsync(ws, 0, 1024, stream);

  cvt_kernel<<<16384, 256, 0, stream>>>((const float4*)x, (ushort4*)xb);
  cvt_kernel<<<90112, 256, 0, stream>>>((const float4*)w13, (ushort4*)w13b);
  cvt_kernel<<<45056, 256, 0, stream>>>((const float4*)w2, (ushort4*)w2b);

  router_kernel<<<2048, 256, 0, stream>>>(x, gw, top_e, top_w, counts);
  scan_kernel<<<1, 64, 0, stream>>>(counts, offs);
  fill_kernel<<<32, 256, 0, stream>>>(top_e, top_w, offs, fillc, row_tok, row_w, row_of);

  gemm1_kernel<<<dim3(22, 32, 8), 512, 0, stream>>>(xb, w13b, row_tok, offs, hb);
  gemm2_kernel<<<dim3(8, 32, 8), 512, 0, stream>>>(hb, w2b, row_w, offs, ybuf);
  combine_kernel<<<8192, 256, 0, stream>>>(ybuf, row_of, out);
}